// Round 7
// baseline (1773.862 us; speedup 1.0000x reference)
//
#include <hip/hip_runtime.h>

#define BB 256
#define TT 1024
#define II 128
#define GG 512   // 2C
#define CC 256
#define L2E 1.44269504f

typedef _Float16 f16;
typedef _Float16 h2_t __attribute__((ext_vector_type(2)));
typedef _Float16 h8_t __attribute__((ext_vector_type(8)));
typedef float f4_t __attribute__((ext_vector_type(4)));
typedef unsigned short ushort_t;
typedef unsigned int uint_t;

static __device__ __forceinline__ float fast_rcp(float x) {
#if __has_builtin(__builtin_amdgcn_rcpf)
    return __builtin_amdgcn_rcpf(x);
#else
    return 1.f / x;
#endif
}
static __device__ __forceinline__ float fast_exp2(float x) {
#if __has_builtin(__builtin_amdgcn_exp2f)
    return __builtin_amdgcn_exp2f(x);
#else
    return exp2f(x);
#endif
}
// half h (0/1) of packed uint -> f32 (compiler emits v_cvt_f32_f16 w/ op_sel)
static __device__ __forceinline__ float f16part(uint_t u, int h) {
    h2_t p = __builtin_bit_cast(h2_t, u);
    return (float)p[h];
}

// ---- kernel 1: Kt[n][k] = f16(kernel[k][n])  (128x512 -> 512x128) ----
__global__ void kt_transpose(const float* __restrict__ kin, f16* __restrict__ kt) {
    int idx = blockIdx.x * 256 + threadIdx.x;   // 65536 total
    int k = idx >> 9;
    int n = idx & 511;
    kt[n * II + k] = (f16)kin[k * GG + n];
}

// ---- kernel 2: xzF = f16((x@K + bias) * s_col) in janet frag-contiguous layout ----
// Layout: xzF[t][g:16][w:4][j8:4][lane:64][j_in:8] (ushort). For batch
// b = g*16 + q*4 + r (lane = q*16+lm), j_in = d*4 + r:
//   j8 0..1: f-col (w + 8*j8 + 4*d)*16 + lm;  j8 2..3: g-col CC + (w + 8*(j8-2) + 4*d)*16 + lm.
// Gemm WG nt produces exactly the j8 == nt slice -> coalesced dwordx4 stores.
__global__ __launch_bounds__(256)
void gemm_xz(const float* __restrict__ x, const f16* __restrict__ kt,
             const float* __restrict__ bias, ushort_t* __restrict__ xzF) {
    const int  nt = blockIdx.x;      // 0..3   (128 cols)
    const long mt = blockIdx.y;      // 0..2047 (128 rows of m' = t*256+b)
    const int wave = threadIdx.x >> 6;
    const int lane = threadIdx.x & 63;
    const int wm = (wave & 1) * 64;
    const int wn = (wave >> 1) * 64;
    const int lm = lane & 15;
    const int q  = lane >> 4;

    f4_t acc[4][4];
#pragma unroll
    for (int mi = 0; mi < 4; ++mi)
#pragma unroll
        for (int ni = 0; ni < 4; ++ni)
            acc[mi][ni] = (f4_t){0.f, 0.f, 0.f, 0.f};

#pragma unroll
    for (int kc = 0; kc < 4; ++kc) {
        h8_t a[4], bf[4];
#pragma unroll
        for (int mi = 0; mi < 4; ++mi) {
            const int rowm = (int)(mt * 128) + wm + mi * 16 + lm;   // m'
            const int b  = rowm & 255;
            const int tt = rowm >> 8;
            const float* ap = x + (size_t)b * (TT * II) + (size_t)tt * II + kc * 32 + q * 8;
            f4_t p0 = *(const f4_t*)ap;
            f4_t p1 = *(const f4_t*)(ap + 4);
            h8_t tv;
            tv[0] = (f16)p0[0]; tv[1] = (f16)p0[1]; tv[2] = (f16)p0[2]; tv[3] = (f16)p0[3];
            tv[4] = (f16)p1[0]; tv[5] = (f16)p1[1]; tv[6] = (f16)p1[2]; tv[7] = (f16)p1[3];
            a[mi] = tv;
        }
#pragma unroll
        for (int ni = 0; ni < 4; ++ni) {
            const f16* bp = kt + (size_t)(nt * 128 + wn + ni * 16 + lm) * II + kc * 32 + q * 8;
            bf[ni] = *(const h8_t*)bp;
        }
#pragma unroll
        for (int mi = 0; mi < 4; ++mi)
#pragma unroll
            for (int ni = 0; ni < 4; ++ni)
                acc[mi][ni] = __builtin_amdgcn_mfma_f32_16x16x32_f16(a[mi], bf[ni], acc[mi][ni], 0, 0, 0);
    }

    // epilogue: frags -> LDS transposed tile st_T[col][row] -> frag-order dwordx4 stores
    __shared__ __align__(16) f16 st_T[128][136];   // row stride 272 B (16B mult), 2-way-conflict pad
#pragma unroll
    for (int mi = 0; mi < 4; ++mi) {
#pragma unroll
        for (int ni = 0; ni < 4; ++ni) {
            const int col = nt * 128 + wn + ni * 16 + lm;
            const float bv = bias[col];
            const float s  = (col < CC) ? L2E : (2.0f * L2E);
#pragma unroll
            for (int r = 0; r < 4; ++r)
                st_T[wn + ni * 16 + lm][wm + mi * 16 + q * 4 + r] = (f16)((acc[mi][ni][r] + bv) * s);
        }
    }
    __syncthreads();
    {
        const int lane_s = threadIdx.x & 63;
        const int q_s = lane_s >> 4, lm_s = lane_s & 15;
        const int t = (int)(mt >> 1);
        const int gbase = (int)(mt & 1) * 8;
#pragma unroll
        for (int c = 0; c < 8; ++c) {
            const int row = (threadIdx.x >> 6) * 8 + c;   // 0..31
            const int g_loc = row >> 2;
            const int w = row & 3;
            uint_t v[4];
#pragma unroll
            for (int d = 0; d < 2; ++d) {
                const f16* lp = &st_T[(w + 4 * d) * 16 + lm_s][g_loc * 16 + q_s * 4];
                uint2 u = *(const uint2*)lp;
                v[d * 2 + 0] = u.x; v[d * 2 + 1] = u.y;
            }
            ushort_t* gp = xzF + ((size_t)t * 16 + gbase + g_loc) * 8192
                               + w * 2048 + nt * 512 + lane_s * 8;
            *(uint4*)gp = make_uint4(v[0], v[1], v[2], v[3]);
        }
    }
}

// ---- kernel 3: MFMA recurrence. 16 WGs x 256 thr (4 waves), 16 batches/WG. ----
// Wave w owns 8 n-tiles: f-cells tau=w+4i, g-cells 256 + (w+4i)*16 (i=0..3).
// R resident: bw[8][8] h8_t = 256 VGPRs -> 1 wave/SIMD.
// h ping-pongs via double-buffered LDS; xzF prefetched 2 steps ahead as
// 4x dwordx4/thread. Raw lgkmcnt-only barrier keeps prefetch in flight.
// NOTE: pf refill MUST come after ALL GATES (R6 bug: GATES(3) read t+2 data).
#define GATES(I, PF, HWR) do {                                                       \
    _Pragma("unroll") for (int r = 0; r < 4; ++r) {                                  \
        float zf = aF[I][r] + f16part((PF)[2 * (I) + (r >> 1)], r & 1);              \
        float zg = aG[I][r] + f16part((PF)[8 + 2 * (I) + (r >> 1)], r & 1);          \
        float ef = fast_exp2(-zf);                                                   \
        float eg = fast_exp2(-fabsf(zg));                                            \
        unsigned sg = __builtin_bit_cast(unsigned, zg) & 0x80000000u;                \
        float t1 = __builtin_bit_cast(float, __builtin_bit_cast(unsigned, ef) ^ sg); \
        float cv = cst[I][r];                                                        \
        float num = fmaf(cv, eg, cv) + fmaf(-t1, eg, t1);                            \
        float den = (1.f + ef) * (1.f + eg);                                         \
        cv = num * fast_rcp(den);                                                    \
        cst[I][r] = cv;                                                              \
        (HWR)[(q * 4 + r) * 264 + (w + 4 * (I)) * 16 + lm] = (f16)cv;                \
    }                                                                                \
} while (0)

#define CHAIN(I) do {                                                                \
    _Pragma("unroll") for (int kt = 0; kt < 8; ++kt) {                               \
        aF[I] = __builtin_amdgcn_mfma_f32_16x16x32_f16(af[kt], bw[I][kt], aF[I], 0, 0, 0);       \
        aG[I] = __builtin_amdgcn_mfma_f32_16x16x32_f16(af[kt], bw[4 + (I)][kt], aG[I], 0, 0, 0); \
    }                                                                                \
} while (0)

#define STEP(T, PF, PP, HRD, HWR) do {                                               \
    h8_t af[8];                                                                      \
    _Pragma("unroll") for (int kt = 0; kt < 8; ++kt)                                 \
        af[kt] = *(const h8_t*)((HRD) + lm * 264 + kt * 32 + q * 8);                 \
    f4_t aF[4], aG[4];                                                               \
    _Pragma("unroll") for (int i = 0; i < 4; ++i) {                                  \
        aF[i] = (f4_t){0.f, 0.f, 0.f, 0.f};                                          \
        aG[i] = (f4_t){0.f, 0.f, 0.f, 0.f};                                          \
    }                                                                                \
    CHAIN(0); CHAIN(1);                                                              \
    GATES(0, PF, HWR);                                                               \
    CHAIN(2);                                                                        \
    GATES(1, PF, HWR);                                                               \
    CHAIN(3);                                                                        \
    GATES(2, PF, HWR);                                                               \
    GATES(3, PF, HWR);                                                               \
    if ((T) + 2 < TT) {                                                              \
        _Pragma("unroll") for (int j8 = 0; j8 < 4; ++j8) {                           \
            uint4 v = *(const uint4*)((PP) + j8 * 512);                              \
            (PF)[j8 * 4 + 0] = v.x; (PF)[j8 * 4 + 1] = v.y;                          \
            (PF)[j8 * 4 + 2] = v.z; (PF)[j8 * 4 + 3] = v.w;                          \
        }                                                                            \
        (PP) += 2 * 131072;                                                          \
    }                                                                                \
    asm volatile("s_waitcnt lgkmcnt(0)\n\ts_barrier" ::: "memory");                  \
} while (0)

__global__ __launch_bounds__(256, 1)
void janet_rec(const float* __restrict__ rk, const float* __restrict__ dw,
               const float* __restrict__ db, const ushort_t* __restrict__ xzF,
               float* __restrict__ out) {
    const int g = blockIdx.x;            // batch group: batches g*16 .. g*16+15
    const int tid = threadIdx.x;
    const int w = tid >> 6;              // wave 0..3
    const int lane = tid & 63;
    const int lm = lane & 15;
    const int q  = lane >> 4;

    // resident pre-scaled recurrent weights:
    // bw[ni8][kt][j] = s * R[kt*32+q*8+j][col(ni8)], col = (w+4*ni8)*16+lm (f)
    //                                              or 256+(w+4*(ni8-4))*16+lm (g)
    h8_t bw[8][8];
#pragma unroll
    for (int ni8 = 0; ni8 < 8; ++ni8) {
        const float s = (ni8 < 4) ? L2E : (2.0f * L2E);
        const int col = (ni8 < 4) ? ((w + 4 * ni8) * 16 + lm)
                                  : (CC + (w + 4 * (ni8 - 4)) * 16 + lm);
#pragma unroll
        for (int kt = 0; kt < 8; ++kt) {
            h8_t tv;
#pragma unroll
            for (int j = 0; j < 8; ++j)
                tv[j] = (f16)(s * rk[(size_t)(kt * 32 + q * 8 + j) * GG + col]);
            bw[ni8][kt] = tv;
        }
    }

    __shared__ __align__(16) f16 hb[2][16][264];
    f16* h0 = &hb[0][0][0];
    f16* h1 = &hb[1][0][0];
    for (int i = tid; i < 2 * 16 * 264; i += 256) ((f16*)hb)[i] = (f16)0.f;

    float cst[4][4];
#pragma unroll
    for (int i = 0; i < 4; ++i)
#pragma unroll
        for (int r = 0; r < 4; ++r) cst[i][r] = 0.f;

    // per-thread xzF base: t-stride 131072 ushorts; j8 offsets immediate (1KB apart)
    const ushort_t* pbase = xzF + (size_t)g * 8192 + w * 2048 + lane * 8;
    const ushort_t* p0 = pbase + 2 * 131072;   // refill source for even t (t=2,4,..)
    const ushort_t* p1 = pbase + 3 * 131072;   // refill source for odd t

    uint_t pf0[16], pf1[16];
#pragma unroll
    for (int j8 = 0; j8 < 4; ++j8) {
        uint4 v0 = *(const uint4*)(pbase + j8 * 512);
        uint4 v1 = *(const uint4*)(pbase + 131072 + j8 * 512);
        pf0[j8 * 4 + 0] = v0.x; pf0[j8 * 4 + 1] = v0.y; pf0[j8 * 4 + 2] = v0.z; pf0[j8 * 4 + 3] = v0.w;
        pf1[j8 * 4 + 0] = v1.x; pf1[j8 * 4 + 1] = v1.y; pf1[j8 * 4 + 2] = v1.z; pf1[j8 * 4 + 3] = v1.w;
    }
    __syncthreads();

#pragma unroll 1
    for (int t = 0; t < TT; t += 2) {
        STEP(t,     pf0, p0, h0, h1);
        STEP(t + 1, pf1, p1, h1, h0);
    }

    // final dense: out[b] = h_final @ dense_w + db
    __shared__ float hf[16][256];
#pragma unroll
    for (int i = 0; i < 4; ++i)
#pragma unroll
        for (int r = 0; r < 4; ++r)
            hf[q * 4 + r][(w + 4 * i) * 16 + lm] = cst[i][r];
    __syncthreads();
    if (tid < 160) {
        const int bi = tid / 10, o = tid % 10;
        float acc = db[o];
#pragma unroll 8
        for (int cc = 0; cc < CC; ++cc) acc = fmaf(hf[bi][cc], dw[cc * 10 + o], acc);
        out[(g * 16 + bi) * 10 + o] = acc;
    }
}

// ---- guard ----
__global__ void ws_too_small(float* out, float wssz) {
    int i = blockIdx.x * 256 + threadIdx.x;
    if (i < BB * 10) out[i] = (i == 0) ? wssz : 0.f;
}

extern "C" void kernel_launch(void* const* d_in, const int* in_sizes, int n_in,
                              void* d_out, int out_size, void* d_ws, size_t ws_size,
                              hipStream_t stream) {
    const float* x   = (const float*)d_in[0];
    const float* kin = (const float*)d_in[1];
    const float* rk  = (const float*)d_in[2];
    const float* rb  = (const float*)d_in[3];
    const float* dw  = (const float*)d_in[4];
    const float* db  = (const float*)d_in[5];
    float* out = (float*)d_out;

    const size_t xz_bytes = (size_t)BB * TT * GG * 2;   // 268,435,456
    const size_t kt_bytes = (size_t)GG * II * 2;        // 131,072
    if (ws_size < xz_bytes + kt_bytes) {
        ws_too_small<<<10, 256, 0, stream>>>(out, (float)ws_size);
        return;
    }

    ushort_t* xzF = (ushort_t*)d_ws;
    f16* kt = (f16*)((char*)d_ws + xz_bytes);

    kt_transpose<<<256, 256, 0, stream>>>(kin, kt);
    gemm_xz<<<dim3(4, 2048), 256, 0, stream>>>(x, kt, rb, xzF);
    janet_rec<<<16, 256, 0, stream>>>(rk, dw, db, xzF, out);
}